// Round 1
// baseline (283.261 us; speedup 1.0000x reference)
//
#include <hip/hip_runtime.h>
#include <math.h>

#define B 8
#define S 128
#define D 256
#define H 8
#define T 129
#define HD 32
#define NEG_INF -1000000000.0f
#define LN_EPS 1e-5f

// ---------------------------------------------------------------------------
// Kernel 1: five row-tiled GEMMs (q,k,v from nv_emb; U,V halves of edge GEMM)
//   which=0: q = nv @ Wq + bq           (1032 x 256)
//   which=1: k = nv @ Wk + bk
//   which=2: v = nv @ Wv + bv
//   which=3: U = desc @ We1[0:256] + be1  (1024 x 256)   (bias folded here)
//   which=4: V = desc @ We1[256:512]      (1024 x 256)
// ---------------------------------------------------------------------------
__global__ __launch_bounds__(256) void gemm5(
    const float* __restrict__ nv, const float* __restrict__ desc,
    const float* __restrict__ Wq, const float* __restrict__ bq,
    const float* __restrict__ Wk, const float* __restrict__ bk,
    const float* __restrict__ Wv, const float* __restrict__ bv,
    const float* __restrict__ We1, const float* __restrict__ be1,
    float* __restrict__ q, float* __restrict__ k, float* __restrict__ v,
    float* __restrict__ U, float* __restrict__ V)
{
    const int which = blockIdx.y;
    const float* X; const float* W; const float* bias; float* out; int rows;
    if (which == 0)      { X = nv;   W = Wq;        bias = bq;  out = q; rows = B*T; }
    else if (which == 1) { X = nv;   W = Wk;        bias = bk;  out = k; rows = B*T; }
    else if (which == 2) { X = nv;   W = Wv;        bias = bv;  out = v; rows = B*T; }
    else if (which == 3) { X = desc; W = We1;       bias = be1; out = U; rows = B*S; }
    else                 { X = desc; W = We1 + D*D; bias = nullptr; out = V; rows = B*S; }

    const int r0  = blockIdx.x * 8;
    const int tid = threadIdx.x;
    __shared__ float xs[8][D];

    #pragma unroll
    for (int r = 0; r < 8; ++r) {
        int rr = r0 + r;
        xs[r][tid] = (rr < rows) ? X[rr * D + tid] : 0.f;
    }
    __syncthreads();

    float acc[8] = {0.f,0.f,0.f,0.f,0.f,0.f,0.f,0.f};
    for (int kk = 0; kk < D; kk += 4) {
        float w0 = W[(kk+0)*D + tid];
        float w1 = W[(kk+1)*D + tid];
        float w2 = W[(kk+2)*D + tid];
        float w3 = W[(kk+3)*D + tid];
        #pragma unroll
        for (int r = 0; r < 8; ++r) {
            float4 x = *(const float4*)&xs[r][kk];
            acc[r] = fmaf(x.x, w0, acc[r]);
            acc[r] = fmaf(x.y, w1, acc[r]);
            acc[r] = fmaf(x.z, w2, acc[r]);
            acc[r] = fmaf(x.w, w3, acc[r]);
        }
    }
    const float bb = bias ? bias[tid] : 0.f;
    #pragma unroll
    for (int r = 0; r < 8; ++r) {
        int rr = r0 + r;
        if (rr < rows) out[rr * D + tid] = acc[r] + bb;
    }
}

// ---------------------------------------------------------------------------
// Kernel 2: small precomputes.
//   qd[b,h,t] = q[b,t,h*32:..] . wa[0:32]
//   kd[b,h,t] = k[b,t,h*32:..] . wa[32:64]
//   W2aT[h, c] = sum_d We2[c, h*32+d] * wa[64+d]   (transposed for LDS layout)
//   econst[h]  = sum_d be2[h*32+d]   * wa[64+d]
// ---------------------------------------------------------------------------
__global__ __launch_bounds__(256) void prep(
    const float* __restrict__ q, const float* __restrict__ k,
    const float* __restrict__ We2, const float* __restrict__ be2,
    const float* __restrict__ wa,
    float* __restrict__ qd, float* __restrict__ kd,
    float* __restrict__ W2aT, float* __restrict__ econst)
{
    const int NQ = B * H * T;
    int id = blockIdx.x * 256 + threadIdx.x;
    if (id < NQ) {
        int b = id / (H*T), rem = id % (H*T), h = rem / T, t = rem % T;
        const float* row = q + (b*T + t)*D + h*HD;
        float s = 0.f;
        #pragma unroll
        for (int d = 0; d < HD; ++d) s = fmaf(row[d], wa[d], s);
        qd[id] = s;
    } else if (id < 2*NQ) {
        int id2 = id - NQ;
        int b = id2 / (H*T), rem = id2 % (H*T), h = rem / T, t = rem % T;
        const float* row = k + (b*T + t)*D + h*HD;
        float s = 0.f;
        #pragma unroll
        for (int d = 0; d < HD; ++d) s = fmaf(row[d], wa[HD + d], s);
        kd[id2] = s;
    } else if (id < 2*NQ + H*D) {
        int id2 = id - 2*NQ;
        int h = id2 / D, c = id2 % D;
        float s = 0.f;
        #pragma unroll
        for (int d = 0; d < HD; ++d) s = fmaf(We2[c*D + h*HD + d], wa[2*HD + d], s);
        W2aT[h*D + c] = s;
    } else if (id < 2*NQ + H*D + H) {
        int h = id - (2*NQ + H*D);
        float s = 0.f;
        #pragma unroll
        for (int d = 0; d < HD; ++d) s = fmaf(be2[h*HD + d], wa[2*HD + d], s);
        econst[h] = s;
    }
}

// ---------------------------------------------------------------------------
// Kernel 3: per-edge LayerNorm + relu + 8-head dot.
// Block = (b, i).  4 waves; each wave owns j = 1+wid, step 4.
//   i==0 : y = U[j-1] + V[j-1]        (cls row; U already holds +be1)
//   i>=1 : y = U[i-1] + V[j-1], skip j==i (masked; never read)
// escore[b,h,i,j] = relu(LN(y)) . W2a[:,h] + econst[h]
// ---------------------------------------------------------------------------
__global__ __launch_bounds__(256) void edge_scores(
    const float* __restrict__ U, const float* __restrict__ V,
    const float* __restrict__ W2aT, const float* __restrict__ econst,
    const float* __restrict__ ln_g, const float* __restrict__ ln_b,
    float* __restrict__ esc)
{
    const int bid = blockIdx.x;      // b*T + i
    const int b = bid / T, i = bid % T;
    const int tid = threadIdx.x, lane = tid & 63, wid = tid >> 6;

    __shared__ float w2[H * D];      // W2aT copy: [h][c], c contiguous
    __shared__ float gl[D], bl[D];
    __shared__ float urow[D];
    __shared__ float ec[H];

    for (int t = tid; t < H * D; t += 256) w2[t] = W2aT[t];
    gl[tid] = ln_g[tid];
    bl[tid] = ln_b[tid];
    if (tid < H) ec[tid] = econst[tid];
    if (i >= 1) urow[tid] = U[(b*S + (i-1))*D + tid];
    __syncthreads();

    const int c0 = lane * 4;         // each lane owns 4 contiguous channels
    for (int j = 1 + wid; j <= S; j += 4) {
        if (i >= 1 && j == i) continue;   // wave-uniform skip

        const float4 v4 = *(const float4*)(V + (b*S + (j-1))*D + c0);
        float4 u4;
        if (i == 0) u4 = *(const float4*)(U + (b*S + (j-1))*D + c0);
        else        u4 = *(const float4*)(urow + c0);

        float y0 = u4.x + v4.x, y1 = u4.y + v4.y, y2 = u4.z + v4.z, y3 = u4.w + v4.w;

        float s1 = y0 + y1 + y2 + y3;
        float s2 = y0*y0 + y1*y1 + y2*y2 + y3*y3;
        #pragma unroll
        for (int m = 32; m >= 1; m >>= 1) {
            s1 += __shfl_xor(s1, m);
            s2 += __shfl_xor(s2, m);
        }
        const float mu  = s1 * (1.f / D);
        const float var = s2 * (1.f / D) - mu * mu;
        const float rs  = rsqrtf(var + LN_EPS);

        const float4 g4 = *(const float4*)(gl + c0);
        const float4 b4 = *(const float4*)(bl + c0);
        float t0 = fmaxf((y0 - mu) * rs * g4.x + b4.x, 0.f);
        float t1 = fmaxf((y1 - mu) * rs * g4.y + b4.y, 0.f);
        float t2 = fmaxf((y2 - mu) * rs * g4.z + b4.z, 0.f);
        float t3 = fmaxf((y3 - mu) * rs * g4.w + b4.w, 0.f);

        float ph[H];
        #pragma unroll
        for (int h = 0; h < H; ++h) {
            const float4 w4 = *(const float4*)(w2 + h*D + c0);
            ph[h] = t0*w4.x + t1*w4.y + t2*w4.z + t3*w4.w;
        }
        #pragma unroll
        for (int h = 0; h < H; ++h)
            #pragma unroll
            for (int m = 32; m >= 1; m >>= 1) ph[h] += __shfl_xor(ph[h], m);

        if (lane == 0) {
            #pragma unroll
            for (int h = 0; h < H; ++h)
                esc[((b*H + h)*T + i)*T + j] = ph[h] + ec[h];
        }
    }
}

// ---------------------------------------------------------------------------
// Kernel 4: logits + softmax + attn write + ctx = attn @ v.
// Block = (i, h, b), 256 threads.
// Mask (adj==0): j==0 always; j==i for i>=1.  Masked attn = exactly 0
// (reference exp underflows to 0.0f as well).
// Prior bias added only for i>=1, j>=1 (valid entries).
// ---------------------------------------------------------------------------
__global__ __launch_bounds__(256) void attn_ctx(
    const float* __restrict__ qd, const float* __restrict__ kd,
    const float* __restrict__ esc, const float* __restrict__ prior,
    const float* __restrict__ v, const float* __restrict__ ba,
    float* __restrict__ out_basis, float* __restrict__ out_attn)
{
    const int i = blockIdx.x, h = blockIdx.y, b = blockIdx.z;
    const int tid = threadIdx.x;
    const int bh = b*H + h;

    __shared__ float p[T];
    __shared__ float red[128];
    __shared__ float mx_s, sum_s;

    float l = NEG_INF;
    bool valid = false;
    if (tid < T) {
        const int j = tid;
        valid = (j >= 1) && !(i >= 1 && j == i);
        if (valid) {
            l = qd[bh*T + i] + kd[bh*T + j] + esc[(bh*T + i)*T + j] + ba[0];
            if (i >= 1) {
                float pr = prior[(bh*S + (i-1))*S + (j-1)];
                pr = fminf(fmaxf(pr, 1e-6f), 1.f - 1e-6f);
                l += logf(pr) - logf(1.f - pr);
            }
        }
        p[tid] = l;
    }
    __syncthreads();

    if (tid < 64) {
        float m = fmaxf(p[tid], p[tid + 64]);
        if (tid == 0) m = fmaxf(m, p[128]);
        #pragma unroll
        for (int mm = 32; mm >= 1; mm >>= 1) m = fmaxf(m, __shfl_xor(m, mm));
        if (tid == 0) mx_s = m;
    }
    __syncthreads();
    const float mx = mx_s;

    float e = 0.f;
    if (tid < T) {
        if (valid) e = expf(l - mx);
        p[tid] = e;
    }
    __syncthreads();

    if (tid < 64) {
        float s = p[tid] + p[tid + 64];
        if (tid == 0) s += p[128];
        #pragma unroll
        for (int mm = 32; mm >= 1; mm >>= 1) s += __shfl_xor(s, mm);
        if (tid == 0) sum_s = s;
    }
    __syncthreads();

    const float inv = 1.f / sum_s;
    if (tid < T) {
        float a = e * inv;
        p[tid] = a;
        out_attn[(bh*T + i)*T + tid] = a;
    }
    __syncthreads();

    if (tid < 128) {
        const int d = tid & 31, jg = tid >> 5;
        float acc = 0.f;
        for (int j = jg; j < T; j += 4)
            acc = fmaf(p[j], v[(b*T + j)*D + h*HD + d], acc);
        red[tid] = acc;
    }
    __syncthreads();
    if (tid < 32) {
        float s = red[tid] + red[tid + 32] + red[tid + 64] + red[tid + 96];
        out_basis[((b*T + i)*H + h)*HD + tid] = s;
    }
}

extern "C" void kernel_launch(void* const* d_in, const int* in_sizes, int n_in,
                              void* d_out, int out_size, void* d_ws, size_t ws_size,
                              hipStream_t stream) {
    const float* desc  = (const float*)d_in[0];
    const float* nv    = (const float*)d_in[1];
    const float* prior = (const float*)d_in[2];
    const float* Wq  = (const float*)d_in[3];
    const float* bq  = (const float*)d_in[4];
    const float* Wk  = (const float*)d_in[5];
    const float* bk  = (const float*)d_in[6];
    const float* Wv  = (const float*)d_in[7];
    const float* bv  = (const float*)d_in[8];
    const float* wa  = (const float*)d_in[9];
    const float* ba  = (const float*)d_in[10];
    const float* We1 = (const float*)d_in[11];
    const float* be1 = (const float*)d_in[12];
    const float* lng = (const float*)d_in[13];
    const float* lnb = (const float*)d_in[14];
    const float* We2 = (const float*)d_in[15];
    const float* be2 = (const float*)d_in[16];

    float* ws = (float*)d_ws;
    float* U    = ws; ws += B*S*D;
    float* V    = ws; ws += B*S*D;
    float* q    = ws; ws += B*T*D;
    float* k    = ws; ws += B*T*D;
    float* v    = ws; ws += B*T*D;
    float* qdw  = ws; ws += B*H*T;
    float* kdw  = ws; ws += B*H*T;
    float* W2aT = ws; ws += H*D;
    float* ec   = ws; ws += H;
    float* esc  = ws; ws += B*H*T*T;

    float* out_basis = (float*)d_out;
    float* out_attn  = out_basis + B*T*H*HD;

    gemm5<<<dim3(129, 5), 256, 0, stream>>>(nv, desc, Wq, bq, Wk, bk, Wv, bv,
                                            We1, be1, q, k, v, U, V);
    prep<<<dim3(73), 256, 0, stream>>>(q, k, We2, be2, wa, qdw, kdw, W2aT, ec);
    edge_scores<<<dim3(B*T), 256, 0, stream>>>(U, V, W2aT, ec, lng, lnb, esc);
    attn_ctx<<<dim3(T, H, B), 256, 0, stream>>>(qdw, kdw, esc, prior, v, ba,
                                                out_basis, out_attn);
}

// Round 2
// 201.618 us; speedup vs baseline: 1.4049x; 1.4049x over previous
//
#include <hip/hip_runtime.h>
#include <math.h>

#define B 8
#define S 128
#define D 256
#define H 8
#define T 129
#define HD 32
#define NEG_INF -1000000000.0f
#define LN_EPS 1e-5f

// ---------------------------------------------------------------------------
// Kernel 1: five row-tiled GEMMs (q,k,v from nv_emb; U,V halves of edge GEMM)
//   which=0: q = nv @ Wq + bq           (1032 x 256)
//   which=1: k = nv @ Wk + bk
//   which=2: v = nv @ Wv + bv
//   which=3: U = desc @ We1[0:256] + be1  (1024 x 256)   (bias folded here)
//   which=4: V = desc @ We1[256:512]      (1024 x 256)
// ---------------------------------------------------------------------------
__global__ __launch_bounds__(256) void gemm5(
    const float* __restrict__ nv, const float* __restrict__ desc,
    const float* __restrict__ Wq, const float* __restrict__ bq,
    const float* __restrict__ Wk, const float* __restrict__ bk,
    const float* __restrict__ Wv, const float* __restrict__ bv,
    const float* __restrict__ We1, const float* __restrict__ be1,
    float* __restrict__ q, float* __restrict__ k, float* __restrict__ v,
    float* __restrict__ U, float* __restrict__ V)
{
    const int which = blockIdx.y;
    const float* X; const float* W; const float* bias; float* out; int rows;
    if (which == 0)      { X = nv;   W = Wq;        bias = bq;  out = q; rows = B*T; }
    else if (which == 1) { X = nv;   W = Wk;        bias = bk;  out = k; rows = B*T; }
    else if (which == 2) { X = nv;   W = Wv;        bias = bv;  out = v; rows = B*T; }
    else if (which == 3) { X = desc; W = We1;       bias = be1; out = U; rows = B*S; }
    else                 { X = desc; W = We1 + D*D; bias = nullptr; out = V; rows = B*S; }

    const int r0  = blockIdx.x * 8;
    const int tid = threadIdx.x;
    __shared__ float xs[8][D];

    #pragma unroll
    for (int r = 0; r < 8; ++r) {
        int rr = r0 + r;
        xs[r][tid] = (rr < rows) ? X[rr * D + tid] : 0.f;
    }
    __syncthreads();

    float acc[8] = {0.f,0.f,0.f,0.f,0.f,0.f,0.f,0.f};
    for (int kk = 0; kk < D; kk += 4) {
        float w0 = W[(kk+0)*D + tid];
        float w1 = W[(kk+1)*D + tid];
        float w2 = W[(kk+2)*D + tid];
        float w3 = W[(kk+3)*D + tid];
        #pragma unroll
        for (int r = 0; r < 8; ++r) {
            float4 x = *(const float4*)&xs[r][kk];
            acc[r] = fmaf(x.x, w0, acc[r]);
            acc[r] = fmaf(x.y, w1, acc[r]);
            acc[r] = fmaf(x.z, w2, acc[r]);
            acc[r] = fmaf(x.w, w3, acc[r]);
        }
    }
    const float bb = bias ? bias[tid] : 0.f;
    #pragma unroll
    for (int r = 0; r < 8; ++r) {
        int rr = r0 + r;
        if (rr < rows) out[rr * D + tid] = acc[r] + bb;
    }
}

// ---------------------------------------------------------------------------
// Kernel 2: small precomputes.
//   qd[b,h,t] = q[b,t,h*32:..] . wa[0:32]
//   kd[b,h,t] = k[b,t,h*32:..] . wa[32:64]
//   W2aT[h, c] = sum_d We2[c, h*32+d] * wa[64+d]   (transposed)
//   econst[h]  = sum_d be2[h*32+d]   * wa[64+d]
// ---------------------------------------------------------------------------
__global__ __launch_bounds__(256) void prep(
    const float* __restrict__ q, const float* __restrict__ k,
    const float* __restrict__ We2, const float* __restrict__ be2,
    const float* __restrict__ wa,
    float* __restrict__ qd, float* __restrict__ kd,
    float* __restrict__ W2aT, float* __restrict__ econst)
{
    const int NQ = B * H * T;
    int id = blockIdx.x * 256 + threadIdx.x;
    if (id < NQ) {
        int b = id / (H*T), rem = id % (H*T), h = rem / T, t = rem % T;
        const float* row = q + (b*T + t)*D + h*HD;
        float s = 0.f;
        #pragma unroll
        for (int d = 0; d < HD; ++d) s = fmaf(row[d], wa[d], s);
        qd[id] = s;
    } else if (id < 2*NQ) {
        int id2 = id - NQ;
        int b = id2 / (H*T), rem = id2 % (H*T), h = rem / T, t = rem % T;
        const float* row = k + (b*T + t)*D + h*HD;
        float s = 0.f;
        #pragma unroll
        for (int d = 0; d < HD; ++d) s = fmaf(row[d], wa[HD + d], s);
        kd[id2] = s;
    } else if (id < 2*NQ + H*D) {
        int id2 = id - 2*NQ;
        int h = id2 / D, c = id2 % D;
        float s = 0.f;
        #pragma unroll
        for (int d = 0; d < HD; ++d) s = fmaf(We2[c*D + h*HD + d], wa[2*HD + d], s);
        W2aT[h*D + c] = s;
    } else if (id < 2*NQ + H*D + H) {
        int h = id - (2*NQ + H*D);
        float s = 0.f;
        #pragma unroll
        for (int d = 0; d < HD; ++d) s = fmaf(be2[h*HD + d], wa[2*HD + d], s);
        econst[h] = s;
    }
}

// ---------------------------------------------------------------------------
// Kernel 3 (v2): per-edge LayerNorm + relu + 8-head dot, zero LDS.
// Grid = (b*T+i, jchunk[0..3]); 256 threads = 4 waves; each wave does 8 j's
// sequentially (j = 1 + chunk*32 + wid*8 + it), one full edge per wave.
// Lane owns 4 contiguous channels (c0 = lane*4); W2aT/g/b/U-row live in
// registers. Head dot reduced with a value-splitting butterfly:
//   masks 1/2/4 send half the 8 partials each step (4+2+1 shfl), then plain
//   xor 8/16/32. Final: lane l<8 holds head hmap(l)=4*b0+2*b1+b2.
// ---------------------------------------------------------------------------
__global__ __launch_bounds__(256) void edge_scores(
    const float* __restrict__ U, const float* __restrict__ V,
    const float* __restrict__ W2aT, const float* __restrict__ econst,
    const float* __restrict__ ln_g, const float* __restrict__ ln_b,
    float* __restrict__ esc)
{
    const int bid = blockIdx.x;      // b*T + i
    const int b = bid / T, i = bid % T;
    const int tid = threadIdx.x, lane = tid & 63, wid = tid >> 6;
    const int c0 = lane * 4;

    const float4 g4 = *(const float4*)(ln_g + c0);
    const float4 b4 = *(const float4*)(ln_b + c0);
    float4 w[H];
    #pragma unroll
    for (int h = 0; h < H; ++h) w[h] = *(const float4*)(W2aT + h*D + c0);
    float4 u4i = make_float4(0.f, 0.f, 0.f, 0.f);
    if (i >= 1) u4i = *(const float4*)(U + (b*S + (i-1))*D + c0);

    const int hmap = 4*(lane&1) + 2*((lane>>1)&1) + ((lane>>2)&1);
    const float ecl = (lane < 8) ? econst[hmap] : 0.f;

    const int j0 = 1 + blockIdx.y*32 + wid*8;
    for (int jj = 0; jj < 8; ++jj) {
        const int j = j0 + jj;                 // 1..128
        if (i >= 1 && j == i) continue;        // wave-uniform skip

        const float4 v4 = *(const float4*)(V + (b*S + (j-1))*D + c0);
        float4 u4;
        if (i == 0) u4 = *(const float4*)(U + (b*S + (j-1))*D + c0);
        else        u4 = u4i;

        const float y0 = u4.x + v4.x, y1 = u4.y + v4.y;
        const float y2 = u4.z + v4.z, y3 = u4.w + v4.w;

        float s1 = y0 + y1 + y2 + y3;
        float s2 = fmaf(y0, y0, fmaf(y1, y1, fmaf(y2, y2, y3 * y3)));
        #pragma unroll
        for (int m = 32; m >= 1; m >>= 1) {
            s1 += __shfl_xor(s1, m);
            s2 += __shfl_xor(s2, m);
        }
        const float mu  = s1 * (1.f / D);
        const float var = s2 * (1.f / D) - mu * mu;
        const float rs  = rsqrtf(var + LN_EPS);

        const float t0 = fmaxf((y0 - mu) * rs * g4.x + b4.x, 0.f);
        const float t1 = fmaxf((y1 - mu) * rs * g4.y + b4.y, 0.f);
        const float t2 = fmaxf((y2 - mu) * rs * g4.z + b4.z, 0.f);
        const float t3 = fmaxf((y3 - mu) * rs * g4.w + b4.w, 0.f);

        float ph[H];
        #pragma unroll
        for (int h = 0; h < H; ++h)
            ph[h] = fmaf(t0, w[h].x, fmaf(t1, w[h].y, fmaf(t2, w[h].z, t3 * w[h].w)));

        // value-splitting butterfly over 8 partials
        {   // mask 1: keep 4
            const bool hi = (lane & 1);
            float k0 = hi ? ph[4] : ph[0], d0 = hi ? ph[0] : ph[4];
            float k1 = hi ? ph[5] : ph[1], d1 = hi ? ph[1] : ph[5];
            float k2 = hi ? ph[6] : ph[2], d2 = hi ? ph[2] : ph[6];
            float k3 = hi ? ph[7] : ph[3], d3 = hi ? ph[3] : ph[7];
            ph[0] = k0 + __shfl_xor(d0, 1);
            ph[1] = k1 + __shfl_xor(d1, 1);
            ph[2] = k2 + __shfl_xor(d2, 1);
            ph[3] = k3 + __shfl_xor(d3, 1);
        }
        {   // mask 2: keep 2
            const bool hi = (lane & 2);
            float k0 = hi ? ph[2] : ph[0], d0 = hi ? ph[0] : ph[2];
            float k1 = hi ? ph[3] : ph[1], d1 = hi ? ph[1] : ph[3];
            ph[0] = k0 + __shfl_xor(d0, 2);
            ph[1] = k1 + __shfl_xor(d1, 2);
        }
        {   // mask 4: keep 1
            const bool hi = (lane & 4);
            float k0 = hi ? ph[1] : ph[0], d0 = hi ? ph[0] : ph[1];
            ph[0] = k0 + __shfl_xor(d0, 4);
        }
        ph[0] += __shfl_xor(ph[0], 8);
        ph[0] += __shfl_xor(ph[0], 16);
        ph[0] += __shfl_xor(ph[0], 32);

        if (lane < 8)
            esc[((b*H + hmap)*T + i)*T + j] = ph[0] + ecl;
    }
}

// ---------------------------------------------------------------------------
// Kernel 4: logits + softmax + attn write + ctx = attn @ v.
// Block = (i, h, b), 256 threads.
// ---------------------------------------------------------------------------
__global__ __launch_bounds__(256) void attn_ctx(
    const float* __restrict__ qd, const float* __restrict__ kd,
    const float* __restrict__ esc, const float* __restrict__ prior,
    const float* __restrict__ v, const float* __restrict__ ba,
    float* __restrict__ out_basis, float* __restrict__ out_attn)
{
    const int i = blockIdx.x, h = blockIdx.y, b = blockIdx.z;
    const int tid = threadIdx.x;
    const int bh = b*H + h;

    __shared__ float p[T];
    __shared__ float red[128];
    __shared__ float mx_s, sum_s;

    float l = NEG_INF;
    bool valid = false;
    if (tid < T) {
        const int j = tid;
        valid = (j >= 1) && !(i >= 1 && j == i);
        if (valid) {
            l = qd[bh*T + i] + kd[bh*T + j] + esc[(bh*T + i)*T + j] + ba[0];
            if (i >= 1) {
                float pr = prior[(bh*S + (i-1))*S + (j-1)];
                pr = fminf(fmaxf(pr, 1e-6f), 1.f - 1e-6f);
                l += logf(pr) - logf(1.f - pr);
            }
        }
        p[tid] = l;
    }
    __syncthreads();

    if (tid < 64) {
        float m = fmaxf(p[tid], p[tid + 64]);
        if (tid == 0) m = fmaxf(m, p[128]);
        #pragma unroll
        for (int mm = 32; mm >= 1; mm >>= 1) m = fmaxf(m, __shfl_xor(m, mm));
        if (tid == 0) mx_s = m;
    }
    __syncthreads();
    const float mx = mx_s;

    float e = 0.f;
    if (tid < T) {
        if (valid) e = expf(l - mx);
        p[tid] = e;
    }
    __syncthreads();

    if (tid < 64) {
        float s = p[tid] + p[tid + 64];
        if (tid == 0) s += p[128];
        #pragma unroll
        for (int mm = 32; mm >= 1; mm >>= 1) s += __shfl_xor(s, mm);
        if (tid == 0) sum_s = s;
    }
    __syncthreads();

    const float inv = 1.f / sum_s;
    if (tid < T) {
        float a = e * inv;
        p[tid] = a;
        out_attn[(bh*T + i)*T + tid] = a;
    }
    __syncthreads();

    if (tid < 128) {
        const int d = tid & 31, jg = tid >> 5;
        float acc = 0.f;
        for (int j = jg; j < T; j += 4)
            acc = fmaf(p[j], v[(b*T + j)*D + h*HD + d], acc);
        red[tid] = acc;
    }
    __syncthreads();
    if (tid < 32) {
        float s = red[tid] + red[tid + 32] + red[tid + 64] + red[tid + 96];
        out_basis[((b*T + i)*H + h)*HD + tid] = s;
    }
}

extern "C" void kernel_launch(void* const* d_in, const int* in_sizes, int n_in,
                              void* d_out, int out_size, void* d_ws, size_t ws_size,
                              hipStream_t stream) {
    const float* desc  = (const float*)d_in[0];
    const float* nv    = (const float*)d_in[1];
    const float* prior = (const float*)d_in[2];
    const float* Wq  = (const float*)d_in[3];
    const float* bq  = (const float*)d_in[4];
    const float* Wk  = (const float*)d_in[5];
    const float* bk  = (const float*)d_in[6];
    const float* Wv  = (const float*)d_in[7];
    const float* bv  = (const float*)d_in[8];
    const float* wa  = (const float*)d_in[9];
    const float* ba  = (const float*)d_in[10];
    const float* We1 = (const float*)d_in[11];
    const float* be1 = (const float*)d_in[12];
    const float* lng = (const float*)d_in[13];
    const float* lnb = (const float*)d_in[14];
    const float* We2 = (const float*)d_in[15];
    const float* be2 = (const float*)d_in[16];

    float* ws = (float*)d_ws;
    float* U    = ws; ws += B*S*D;
    float* V    = ws; ws += B*S*D;
    float* q    = ws; ws += B*T*D;
    float* k    = ws; ws += B*T*D;
    float* v    = ws; ws += B*T*D;
    float* qdw  = ws; ws += B*H*T;
    float* kdw  = ws; ws += B*H*T;
    float* W2aT = ws; ws += H*D;
    float* ec   = ws; ws += H;
    float* esc  = ws; ws += B*H*T*T;

    float* out_basis = (float*)d_out;
    float* out_attn  = out_basis + B*T*H*HD;

    gemm5<<<dim3(129, 5), 256, 0, stream>>>(nv, desc, Wq, bq, Wk, bk, Wv, bv,
                                            We1, be1, q, k, v, U, V);
    prep<<<dim3(73), 256, 0, stream>>>(q, k, We2, be2, wa, qdw, kdw, W2aT, ec);
    edge_scores<<<dim3(B*T, 4), 256, 0, stream>>>(U, V, W2aT, ec, lng, lnb, esc);
    attn_ctx<<<dim3(T, H, B), 256, 0, stream>>>(qdw, kdw, esc, prior, v, ba,
                                                out_basis, out_attn);
}

// Round 3
// 174.306 us; speedup vs baseline: 1.6251x; 1.1567x over previous
//
#include <hip/hip_runtime.h>
#include <math.h>

#define B 8
#define S 128
#define D 256
#define H 8
#define T 129
#define HD 32
#define NEG_INF -1000000000.0f
#define LN_EPS 1e-5f

// ---------------------------------------------------------------------------
// Kernel 1: weight folds (tiny).
//   Wqk[c*16 + h]   = sum_d Wq[c, h*32+d] * wa[d]        (h=0..7)
//   Wqk[c*16 + 8+h] = sum_d Wk[c, h*32+d] * wa[32+d]
//   bqk[h]          = sum_d bq[h*32+d]    * wa[d]
//   bqk[8+h]        = sum_d bk[h*32+d]    * wa[32+d]
//   W2aT[h*D + c]   = sum_d We2[c, h*32+d]* wa[64+d]
//   econst[h]       = sum_d be2[h*32+d]   * wa[64+d]
// ---------------------------------------------------------------------------
__global__ __launch_bounds__(256) void prep_w(
    const float* __restrict__ Wq, const float* __restrict__ bq,
    const float* __restrict__ Wk, const float* __restrict__ bk,
    const float* __restrict__ We2, const float* __restrict__ be2,
    const float* __restrict__ wa,
    float* __restrict__ Wqk, float* __restrict__ bqk,
    float* __restrict__ W2aT, float* __restrict__ econst)
{
    int id = blockIdx.x * 256 + threadIdx.x;
    if (id < 2048) {
        int c = id >> 3, h = id & 7;
        float s = 0.f;
        #pragma unroll
        for (int d = 0; d < HD; ++d) s = fmaf(Wq[c*D + h*HD + d], wa[d], s);
        Wqk[c*16 + h] = s;
    } else if (id < 4096) {
        int id2 = id - 2048; int c = id2 >> 3, h = id2 & 7;
        float s = 0.f;
        #pragma unroll
        for (int d = 0; d < HD; ++d) s = fmaf(Wk[c*D + h*HD + d], wa[HD + d], s);
        Wqk[c*16 + 8 + h] = s;
    } else if (id < 6144) {
        int id2 = id - 4096; int h = id2 / D, c = id2 % D;
        float s = 0.f;
        #pragma unroll
        for (int d = 0; d < HD; ++d) s = fmaf(We2[c*D + h*HD + d], wa[2*HD + d], s);
        W2aT[h*D + c] = s;
    } else if (id < 6152) {
        int h = id - 6144;
        float s = 0.f;
        #pragma unroll
        for (int d = 0; d < HD; ++d) s = fmaf(bq[h*HD + d], wa[d], s);
        bqk[h] = s;
    } else if (id < 6160) {
        int h = id - 6152;
        float s = 0.f;
        #pragma unroll
        for (int d = 0; d < HD; ++d) s = fmaf(bk[h*HD + d], wa[HD + d], s);
        bqk[8 + h] = s;
    } else if (id < 6168) {
        int h = id - 6160;
        float s = 0.f;
        #pragma unroll
        for (int d = 0; d < HD; ++d) s = fmaf(be2[h*HD + d], wa[2*HD + d], s);
        econst[h] = s;
    }
}

// ---------------------------------------------------------------------------
// Kernel 2: three row-tiled GEMMs (v; U,V halves of edge GEMM)
// ---------------------------------------------------------------------------
__global__ __launch_bounds__(256) void gemm3(
    const float* __restrict__ nv, const float* __restrict__ desc,
    const float* __restrict__ Wv, const float* __restrict__ bv,
    const float* __restrict__ We1, const float* __restrict__ be1,
    float* __restrict__ v, float* __restrict__ U, float* __restrict__ V)
{
    const int which = blockIdx.y;
    const float* X; const float* W; const float* bias; float* out; int rows;
    if (which == 0)      { X = nv;   W = Wv;        bias = bv;  out = v; rows = B*T; }
    else if (which == 1) { X = desc; W = We1;       bias = be1; out = U; rows = B*S; }
    else                 { X = desc; W = We1 + D*D; bias = nullptr; out = V; rows = B*S; }

    const int r0  = blockIdx.x * 8;
    const int tid = threadIdx.x;
    __shared__ float xs[8][D];

    #pragma unroll
    for (int r = 0; r < 8; ++r) {
        int rr = r0 + r;
        xs[r][tid] = (rr < rows) ? X[rr * D + tid] : 0.f;
    }
    __syncthreads();

    float acc[8] = {0.f,0.f,0.f,0.f,0.f,0.f,0.f,0.f};
    for (int kk = 0; kk < D; kk += 4) {
        float w0 = W[(kk+0)*D + tid];
        float w1 = W[(kk+1)*D + tid];
        float w2 = W[(kk+2)*D + tid];
        float w3 = W[(kk+3)*D + tid];
        #pragma unroll
        for (int r = 0; r < 8; ++r) {
            float4 x = *(const float4*)&xs[r][kk];
            acc[r] = fmaf(x.x, w0, acc[r]);
            acc[r] = fmaf(x.y, w1, acc[r]);
            acc[r] = fmaf(x.z, w2, acc[r]);
            acc[r] = fmaf(x.w, w3, acc[r]);
        }
    }
    const float bb = bias ? bias[tid] : 0.f;
    #pragma unroll
    for (int r = 0; r < 8; ++r) {
        int rr = r0 + r;
        if (rr < rows) out[rr * D + tid] = acc[r] + bb;
    }
}

// ---------------------------------------------------------------------------
// Kernel 3: qdkd[t*16 + c] = nv[t,:] @ Wqk[:,c] + bqk[c]   (1032 x 256 x 16)
// Block: 16 rows x 16 cols.
// ---------------------------------------------------------------------------
__global__ __launch_bounds__(256) void qdkd_gemm(
    const float* __restrict__ nv, const float* __restrict__ Wqk,
    const float* __restrict__ bqk, float* __restrict__ qdkd)
{
    const int r0 = blockIdx.x * 16;
    const int tid = threadIdx.x;
    const int r = tid >> 4, c = tid & 15;
    __shared__ float xs[16][D];

    for (int t = tid; t < 16 * D; t += 256) {
        int rr = r0 + (t >> 8);
        xs[t >> 8][t & 255] = (rr < B*T) ? nv[rr * D + (t & 255)] : 0.f;
    }
    __syncthreads();

    float acc = 0.f;
    for (int kk = 0; kk < D; kk += 4) {
        float4 x = *(const float4*)&xs[r][kk];
        acc = fmaf(x.x, Wqk[(kk+0)*16 + c], acc);
        acc = fmaf(x.y, Wqk[(kk+1)*16 + c], acc);
        acc = fmaf(x.z, Wqk[(kk+2)*16 + c], acc);
        acc = fmaf(x.w, Wqk[(kk+3)*16 + c], acc);
    }
    const int rr = r0 + r;
    if (rr < B*T) qdkd[rr * 16 + c] = acc + bqk[c];
}

// ---------------------------------------------------------------------------
// Kernel 4 (fused): edge LN+relu+head-dot  ->  softmax(+prior)  ->  ctx.
// Block = (b*T + i), 512 threads = 8 waves.
//  Phase A: wave w computes scores for j = 1+16w .. 16+16w  -> escl[h][j] LDS
//  Phase B: wave h does softmax for head h (j1=1+lane, j2=65+lane)
//  Phase C: thread (h=wid, d=lane&31, half=lane>>5) does ctx over 64 j's
// ---------------------------------------------------------------------------
__global__ __launch_bounds__(512) void edge_attn(
    const float* __restrict__ U, const float* __restrict__ V,
    const float* __restrict__ W2aT, const float* __restrict__ econst,
    const float* __restrict__ ln_g, const float* __restrict__ ln_b,
    const float* __restrict__ qdkd, const float* __restrict__ prior,
    const float* __restrict__ v, const float* __restrict__ ba,
    float* __restrict__ out_basis, float* __restrict__ out_attn)
{
    const int bid = blockIdx.x;      // b*T + i
    const int b = bid / T, i = bid % T;
    const int tid = threadIdx.x, lane = tid & 63, wid = tid >> 6;
    const int c0 = lane * 4;

    __shared__ float escl[H][132];
    __shared__ float pat[H][132];

    // ---- Phase A: edge scores ----
    const float4 g4 = *(const float4*)(ln_g + c0);
    const float4 b4 = *(const float4*)(ln_b + c0);
    float4 w[H];
    #pragma unroll
    for (int h = 0; h < H; ++h) w[h] = *(const float4*)(W2aT + h*D + c0);
    float4 u4i = make_float4(0.f, 0.f, 0.f, 0.f);
    if (i >= 1) u4i = *(const float4*)(U + (b*S + (i-1))*D + c0);

    const int hmap = 4*(lane&1) + 2*((lane>>1)&1) + ((lane>>2)&1);
    const float ecl = (lane < 8) ? econst[hmap] : 0.f;

    const int j0 = 1 + wid * 16;
    for (int jj = 0; jj < 16; ++jj) {
        const int j = j0 + jj;                 // 1..128
        if (i >= 1 && j == i) continue;        // wave-uniform skip (never read)

        const float4 v4 = *(const float4*)(V + (b*S + (j-1))*D + c0);
        float4 u4;
        if (i == 0) u4 = *(const float4*)(U + (b*S + (j-1))*D + c0);
        else        u4 = u4i;

        const float y0 = u4.x + v4.x, y1 = u4.y + v4.y;
        const float y2 = u4.z + v4.z, y3 = u4.w + v4.w;

        float s1 = y0 + y1 + y2 + y3;
        float s2 = fmaf(y0, y0, fmaf(y1, y1, fmaf(y2, y2, y3 * y3)));
        #pragma unroll
        for (int m = 32; m >= 1; m >>= 1) {
            s1 += __shfl_xor(s1, m);
            s2 += __shfl_xor(s2, m);
        }
        const float mu  = s1 * (1.f / D);
        const float var = s2 * (1.f / D) - mu * mu;
        const float rs  = rsqrtf(var + LN_EPS);

        const float t0 = fmaxf((y0 - mu) * rs * g4.x + b4.x, 0.f);
        const float t1 = fmaxf((y1 - mu) * rs * g4.y + b4.y, 0.f);
        const float t2 = fmaxf((y2 - mu) * rs * g4.z + b4.z, 0.f);
        const float t3 = fmaxf((y3 - mu) * rs * g4.w + b4.w, 0.f);

        float ph[H];
        #pragma unroll
        for (int h = 0; h < H; ++h)
            ph[h] = fmaf(t0, w[h].x, fmaf(t1, w[h].y, fmaf(t2, w[h].z, t3 * w[h].w)));

        // value-splitting butterfly over 8 partials
        {
            const bool hi = (lane & 1);
            float k0 = hi ? ph[4] : ph[0], d0 = hi ? ph[0] : ph[4];
            float k1 = hi ? ph[5] : ph[1], d1 = hi ? ph[1] : ph[5];
            float k2 = hi ? ph[6] : ph[2], d2 = hi ? ph[2] : ph[6];
            float k3 = hi ? ph[7] : ph[3], d3 = hi ? ph[3] : ph[7];
            ph[0] = k0 + __shfl_xor(d0, 1);
            ph[1] = k1 + __shfl_xor(d1, 1);
            ph[2] = k2 + __shfl_xor(d2, 1);
            ph[3] = k3 + __shfl_xor(d3, 1);
        }
        {
            const bool hi = (lane & 2);
            float k0 = hi ? ph[2] : ph[0], d0 = hi ? ph[0] : ph[2];
            float k1 = hi ? ph[3] : ph[1], d1 = hi ? ph[1] : ph[3];
            ph[0] = k0 + __shfl_xor(d0, 2);
            ph[1] = k1 + __shfl_xor(d1, 2);
        }
        {
            const bool hi = (lane & 4);
            float k0 = hi ? ph[1] : ph[0], d0 = hi ? ph[0] : ph[1];
            ph[0] = k0 + __shfl_xor(d0, 4);
        }
        ph[0] += __shfl_xor(ph[0], 8);
        ph[0] += __shfl_xor(ph[0], 16);
        ph[0] += __shfl_xor(ph[0], 32);

        if (lane < 8) escl[hmap][j] = ph[0] + ecl;
    }
    __syncthreads();

    // ---- Phase B: softmax (wave = head) ----
    const int h = wid;
    const int bh = b*H + h;
    const float qdv = qdkd[(b*T + i)*16 + h];
    const float ba0 = ba[0];
    const int j1 = 1 + lane, j2 = 65 + lane;
    const bool v1 = !(i >= 1 && j1 == i);
    const bool v2 = !(i >= 1 && j2 == i);

    float l1 = NEG_INF, l2 = NEG_INF;
    if (v1) {
        l1 = qdv + qdkd[(b*T + j1)*16 + 8 + h] + escl[h][j1] + ba0;
        if (i >= 1) {
            float pr = prior[(bh*S + (i-1))*S + (j1-1)];
            pr = fminf(fmaxf(pr, 1e-6f), 1.f - 1e-6f);
            l1 += logf(pr) - logf(1.f - pr);
        }
    }
    if (v2) {
        l2 = qdv + qdkd[(b*T + j2)*16 + 8 + h] + escl[h][j2] + ba0;
        if (i >= 1) {
            float pr = prior[(bh*S + (i-1))*S + (j2-1)];
            pr = fminf(fmaxf(pr, 1e-6f), 1.f - 1e-6f);
            l2 += logf(pr) - logf(1.f - pr);
        }
    }

    float m = fmaxf(l1, l2);
    #pragma unroll
    for (int mm = 32; mm >= 1; mm >>= 1) m = fmaxf(m, __shfl_xor(m, mm));
    const float e1 = v1 ? expf(l1 - m) : 0.f;
    const float e2 = v2 ? expf(l2 - m) : 0.f;
    float s = e1 + e2;
    #pragma unroll
    for (int mm = 32; mm >= 1; mm >>= 1) s += __shfl_xor(s, mm);
    const float inv = 1.f / s;
    const float a1 = e1 * inv, a2 = e2 * inv;

    float* arow = out_attn + (size_t)(bh*T + i)*T;
    arow[j1] = a1;
    arow[j2] = a2;
    if (lane == 0) arow[0] = 0.f;
    pat[h][j1] = a1;
    pat[h][j2] = a2;
    __syncthreads();

    // ---- Phase C: ctx ----
    const int d = lane & 31, half = lane >> 5;
    float acc = 0.f;
    const float* vb = v + (size_t)(b*T)*D + h*HD + d;
    #pragma unroll 4
    for (int jj = 0; jj < 64; ++jj) {
        const int j = 1 + half*64 + jj;
        acc = fmaf(pat[h][j], vb[j*D], acc);
    }
    acc += __shfl_xor(acc, 32);
    if (lane < 32)
        out_basis[((b*T + i)*H + h)*HD + d] = acc;
}

extern "C" void kernel_launch(void* const* d_in, const int* in_sizes, int n_in,
                              void* d_out, int out_size, void* d_ws, size_t ws_size,
                              hipStream_t stream) {
    const float* desc  = (const float*)d_in[0];
    const float* nv    = (const float*)d_in[1];
    const float* prior = (const float*)d_in[2];
    const float* Wq  = (const float*)d_in[3];
    const float* bq  = (const float*)d_in[4];
    const float* Wk  = (const float*)d_in[5];
    const float* bk  = (const float*)d_in[6];
    const float* Wv  = (const float*)d_in[7];
    const float* bv  = (const float*)d_in[8];
    const float* wa  = (const float*)d_in[9];
    const float* ba  = (const float*)d_in[10];
    const float* We1 = (const float*)d_in[11];
    const float* be1 = (const float*)d_in[12];
    const float* lng = (const float*)d_in[13];
    const float* lnb = (const float*)d_in[14];
    const float* We2 = (const float*)d_in[15];
    const float* be2 = (const float*)d_in[16];

    float* ws = (float*)d_ws;
    float* U    = ws; ws += B*S*D;
    float* V    = ws; ws += B*S*D;
    float* v    = ws; ws += B*T*D;
    float* Wqk  = ws; ws += D*16;
    float* bqk  = ws; ws += 16;
    float* W2aT = ws; ws += H*D;
    float* ec   = ws; ws += H;
    float* qdkd = ws; ws += B*T*16;

    float* out_basis = (float*)d_out;
    float* out_attn  = out_basis + B*T*H*HD;

    prep_w<<<dim3(25), 256, 0, stream>>>(Wq, bq, Wk, bk, We2, be2, wa,
                                         Wqk, bqk, W2aT, ec);
    gemm3<<<dim3(129, 3), 256, 0, stream>>>(nv, desc, Wv, bv, We1, be1, v, U, V);
    qdkd_gemm<<<dim3(65), 256, 0, stream>>>(nv, Wqk, bqk, qdkd);
    edge_attn<<<dim3(B*T), 512, 0, stream>>>(U, V, W2aT, ec, lng, lnb,
                                             qdkd, prior, v, ba,
                                             out_basis, out_attn);
}